// Round 2
// baseline (229.607 us; speedup 1.0000x reference)
//
#include <hip/hip_runtime.h>
#include <hip/hip_bf16.h>

// Problem constants (from reference)
#define BATCH_N   16384
#define FEAT      128      // MOVIE_FEAT == USER_FEAT
#define NNBR      50
#define NUM_MOVIES_N 100000

typedef short  short8  __attribute__((ext_vector_type(8)));
typedef float  floatx4 __attribute__((ext_vector_type(4)));
typedef unsigned int u32;

__device__ __forceinline__ __hip_bfloat16 f2bf(float x) { return __float2bfloat16(x); }
__device__ __forceinline__ float bfb2f(short s) {
  union { u32 u; float f; } c; c.u = ((u32)(unsigned short)s) << 16; return c.f;
}

// async global->LDS 16B DMA. LDS dst must be wave-uniform base + lane*16
// (m104), so the XOR swizzle is applied to the SOURCE index.
__device__ __forceinline__ void gld16(const __hip_bfloat16* g, __hip_bfloat16* l) {
  __builtin_amdgcn_global_load_lds(
      (const __attribute__((address_space(1))) u32*)g,
      (__attribute__((address_space(3))) u32*)l, 16, 0, 0);
}

__device__ __forceinline__ floatx4 mfma16(short8 a, short8 b, floatx4 c) {
  return __builtin_amdgcn_mfma_f32_16x16x32_bf16(a, b, c, 0, 0, 0);
}

// ---------------------------------------------------------------------------
// prep_all: fused (a) fp32 movie_table -> bf16 copy and (b) bf16 transposed
// weights Wt[n][k] + fused bias bu+bm. One launch instead of two.
// blocks [0,6250): conv;  [6250,6506): weight prep.
// ---------------------------------------------------------------------------
#define CONV_BLOCKS (NUM_MOVIES_N * FEAT / (256 * 8))   // 6250
__global__ __launch_bounds__(256) void prep_all(
    const float* __restrict__ t, __hip_bfloat16* __restrict__ tb,
    const float* __restrict__ Wu, const float* __restrict__ Wm,
    const float* __restrict__ W1, const float* __restrict__ W2,
    const float* __restrict__ bu, const float* __restrict__ bm,
    __hip_bfloat16* __restrict__ WcatT, __hip_bfloat16* __restrict__ WmT,
    __hip_bfloat16* __restrict__ W1T,  __hip_bfloat16* __restrict__ W2T,
    float* __restrict__ bc) {
  int bid = blockIdx.x;
  if (bid < CONV_BLOCKS) {
    size_t i = ((size_t)bid * 256 + threadIdx.x) * 8;
    float4 v0 = *(const float4*)(t + i);
    float4 v1 = *(const float4*)(t + i + 4);
    __hip_bfloat16 o[8];
    o[0] = f2bf(v0.x); o[1] = f2bf(v0.y); o[2] = f2bf(v0.z); o[3] = f2bf(v0.w);
    o[4] = f2bf(v1.x); o[5] = f2bf(v1.y); o[6] = f2bf(v1.z); o[7] = f2bf(v1.w);
    *(short8*)(tb + i) = *(short8*)o;
  } else {
    int idx = (bid - CONV_BLOCKS) * 256 + threadIdx.x;   // 0..65535
    int n = idx & 255, k = idx >> 8;
    float v = (k < 128) ? Wu[k * 256 + n] : Wm[(k - 128) * 256 + n];
    WcatT[n * 256 + k] = f2bf(v);
    W1T[n * 256 + k]   = f2bf(W1[k * 256 + n]);
    if (k < 128) WmT[n * 128 + k] = f2bf(Wm[k * 256 + n]);
    if (idx < 32768) {
      int k2 = idx >> 7, n2 = idx & 127;
      W2T[n2 * 256 + k2] = f2bf(W2[k2 * 128 + n2]);
    }
    if (idx < 256) bc[idx] = bu[idx] + bm[idx];
  }
}

// ---------------------------------------------------------------------------
// layer: one GEMM layer on a 64-row LDS tile with B persistent in VGPRs.
//   Ain (LDS): 64 rows x K0, XOR-swizzled (16B slot s holds chunk s^(r&7)).
//   Wt: global [NCOL][K0] bf16 (L2-hot; ~16 KB/wave loaded ONCE per layer).
// 8 waves split N: wave w owns JN*16 cols (JN = NCOL/128).
// 4 iters x 16 rows: KK ds_read_b128 + 2*KK*JN MFMA; epilogue -> LDS
// (swizzled, 256-col) or global fp32 (128-col).
// ---------------------------------------------------------------------------
template <int K0, int NCOL, bool RELU, bool TOGLB>
__device__ __forceinline__ void layer(
    const __hip_bfloat16* Ain,
    const __hip_bfloat16* __restrict__ Wt, const float* __restrict__ bias,
    __hip_bfloat16* Olds, float* __restrict__ Oglb,
    int wid, int quad, int lrow) {
  constexpr int KK = K0 / 32;
  constexpr int JN = NCOL / 128;
  const int c0 = wid * JN * 16;

  short8 bfr[JN][KK];
  float  bv[JN];
  #pragma unroll
  for (int j = 0; j < JN; ++j) {
    #pragma unroll
    for (int kc = 0; kc < KK; ++kc)
      bfr[j][kc] = *(const short8*)(Wt + (size_t)(c0 + j * 16 + lrow) * K0 +
                                    kc * 32 + quad * 8);
    bv[j] = bias[c0 + j * 16 + lrow];
  }

  #pragma unroll
  for (int it = 0; it < 4; ++it) {
    int r = it * 16 + lrow;
    short8 af[KK];
    #pragma unroll
    for (int kc = 0; kc < KK; ++kc)
      af[kc] = *(const short8*)&Ain[r * K0 + (((kc * 4 + quad) ^ (r & 7)) << 3)];
    floatx4 pa[JN], pb[JN];
    #pragma unroll
    for (int j = 0; j < JN; ++j) { pa[j] = {}; pb[j] = {}; }
    #pragma unroll
    for (int kc = 0; kc < KK; kc += 2)
      #pragma unroll
      for (int j = 0; j < JN; ++j) {
        pa[j] = mfma16(af[kc],     bfr[j][kc],     pa[j]);
        pb[j] = mfma16(af[kc + 1], bfr[j][kc + 1], pb[j]);
      }
    #pragma unroll
    for (int j = 0; j < JN; ++j) {
      floatx4 a = pa[j] + pb[j];
      int col = c0 + j * 16 + lrow;
      #pragma unroll
      for (int rr = 0; rr < 4; ++rr) {
        int row = it * 16 + quad * 4 + rr;
        float v = a[rr] + bv[j];
        if (RELU) v = fmaxf(v, 0.f);
        if (TOGLB) {
          Oglb[(size_t)row * NCOL + col] = v;
        } else {
          int ch = col >> 3;
          Olds[row * 256 + (((ch ^ (row & 7)) << 3) | (col & 7))] = f2bf(v);
        }
      }
    }
  }
}

// ---------------------------------------------------------------------------
// fused_mlp: one block = 64 rows of stream s (0 user / 1 pos / 2 neg),
// all 3 layers; B per layer in VGPRs, A/E/H in LDS; 3 barriers per block.
//
// R12 (this round): the R11 in-block gather was starved by the
// waves_per_eu(2,2) pin (1 block/CU -> only 8 waves x 13 gather loads in
// flight; the old standalone gather_user had ~2-4x that MLP). VGPR_Count is
// 100, which fits the 128-reg budget of 4 waves/EU, and LDS is 64 KB/block,
// so 2 blocks/CU is free: pin amdgpu_waves_per_eu(4,4). Also front-load the
// gather: s==0 is blocks [0,256) so ALL gathers start at t=0 co-resident
// with 256 pos/neg MFMA blocks, instead of trickling in 1-of-3.
// (R10 history: launch_bounds(512,2) alone let the scheduler pick its own
// target and cap VGPRs at 88, sinking B-loads. (4,4) pins a 128-reg budget
// >= the 100 actually in use; if VGPR_Count comes back <=90 that failure
// mode recurred.)
// ---------------------------------------------------------------------------
__global__ __launch_bounds__(512)
__attribute__((amdgpu_waves_per_eu(4, 4)))
void fused_mlp(
    const float* __restrict__ users,
    const __hip_bfloat16* __restrict__ tb,
    const int* __restrict__ pos_ids, const int* __restrict__ neg_ids,
    const int* __restrict__ nbr_ids,
    const __hip_bfloat16* __restrict__ WcatT,
    const __hip_bfloat16* __restrict__ WmT,
    const __hip_bfloat16* __restrict__ W1T,
    const __hip_bfloat16* __restrict__ W2T,
    const float* __restrict__ bc, const float* __restrict__ bmv,
    const float* __restrict__ b1, const float* __restrict__ b2,
    float* __restrict__ out) {
  __shared__ __hip_bfloat16 A_lds[64 * 256];   // 32 KB: A, then H
  __shared__ __hip_bfloat16 E_lds[64 * 256];   // 32 KB: E

  const int t    = threadIdx.x;
  const int lane = t & 63, wid = t >> 6;       // wid 0..7
  const int quad = lane >> 4, lrow = lane & 15;

  // front-loaded stream mapping: [0,256) -> s0; [256,768) -> s1/s2 interleaved
  int s, tile;
  if (blockIdx.x < 256) { s = 0; tile = blockIdx.x; }
  else { int k = blockIdx.x - 256; s = 1 + (k & 1); tile = k >> 1; }
  const long m0 = (long)tile * 64;

  // ---- stage A tile ----
  if (s == 0) {
    // in-block neighbor gather + user convert (was gather_user kernel).
    for (int rr = 0; rr < 8; ++rr) {
      const int r = (wid << 3) | rr;
      const size_t grow = (size_t)(m0 + r);
      const int* nb = nbr_ids + grow * NNBR;
      float acc[8] = {0.f, 0.f, 0.f, 0.f, 0.f, 0.f, 0.f, 0.f};
      #pragma unroll
      for (int it = 0; it < 13; ++it) {
        int j = (it << 2) + quad;
        if (j < NNBR) {
          int id = nb[j];
          short8 v = *(const short8*)(tb + (size_t)id * FEAT + (lrow << 3));
          #pragma unroll
          for (int e = 0; e < 8; ++e) acc[e] += bfb2f(v[e]);
        }
      }
      __hip_bfloat16 o[8];
      #pragma unroll
      for (int e = 0; e < 8; ++e) {
        float v = acc[e];
        v += __shfl_xor(v, 16, 64);
        v += __shfl_xor(v, 32, 64);
        o[e] = f2bf(v * (1.f / NNBR));
      }
      if (quad == 0) {
        int ch = 16 + lrow;                    // cols [128,256), one 16B chunk
        *(short8*)(A_lds + r * 256 + ((ch ^ (r & 7)) << 3)) = *(short8*)o;
      }
      // users fp32 -> bf16, cols [0,128): lane covers 2 consecutive cols
      float2 uv = ((const float2*)(users + grow * FEAT))[lane];
      __hip_bfloat162 t0; t0.x = f2bf(uv.x); t0.y = f2bf(uv.y);
      int col = lane << 1, ch2 = col >> 3;
      *(__hip_bfloat162*)(A_lds + r * 256 + ((ch2 ^ (r & 7)) << 3) + (col & 7)) = t0;
    }
  } else {
    const int* ids = (s == 1) ? pos_ids : neg_ids;
    #pragma unroll
    for (int i = 0; i < 2; ++i) {
      int c = t + i * 512;                     // 1024 slots: r=c>>4, sl=c&15
      int r = c >> 4, sl = c & 15;
      int id = ids[m0 + r];
      gld16(tb + ((size_t)id << 7) + ((sl ^ (r & 7)) << 3),
            A_lds + (c << 3));
    }
  }
  __syncthreads();                             // A staged (vmcnt(0) drain / LDS writes)

  // ---- layer 0 -> E_lds (no relu) ----
  if (s == 0)
    layer<256, 256, false, false>(A_lds, WcatT, bc, E_lds, nullptr,
                                  wid, quad, lrow);
  else
    layer<128, 256, false, false>(A_lds, WmT, bmv, E_lds, nullptr,
                                  wid, quad, lrow);
  __syncthreads();                             // E complete (A reads done)

  // ---- layer 1: H = relu(E @ W1^T + b1) -> A_lds ----
  layer<256, 256, true, false>(E_lds, W1T, b1, A_lds, nullptr,
                               wid, quad, lrow);
  __syncthreads();                             // H complete

  // ---- layer 2: out = relu(H @ W2^T + b2) -> global fp32 ----
  layer<256, 128, true, true>(A_lds, W2T, b2, nullptr,
                              out + ((size_t)s * BATCH_N + m0) * 128,
                              wid, quad, lrow);
}

// ---------------------------------------------------------------------------
extern "C" void kernel_launch(void* const* d_in, const int* in_sizes, int n_in,
                              void* d_out, int out_size, void* d_ws, size_t ws_size,
                              hipStream_t stream) {
  const float* users   = (const float*)d_in[0];
  // d_in[1] pos_movies, d_in[2] neg_movies, d_in[3] user_ids: unused by ref
  const int*   pos_ids = (const int*)d_in[4];
  const int*   neg_ids = (const int*)d_in[5];
  const int*   nbr_ids = (const int*)d_in[6];
  const float* table   = (const float*)d_in[7];
  const float* Wu = (const float*)d_in[8];
  const float* bu = (const float*)d_in[9];
  const float* Wm = (const float*)d_in[10];
  const float* bm = (const float*)d_in[11];
  const float* W1 = (const float*)d_in[12];
  const float* b1 = (const float*)d_in[13];
  const float* W2 = (const float*)d_in[14];
  const float* b2 = (const float*)d_in[15];
  float* out = (float*)d_out;

  // workspace carve (all 256B aligned). Total ~26 MB.
  char* p = (char*)d_ws;
  auto carve = [&](size_t bytes) { char* r = p; p += (bytes + 255) & ~(size_t)255; return r; };
  __hip_bfloat16* tb     = (__hip_bfloat16*)carve((size_t)NUM_MOVIES_N * FEAT * 2);
  __hip_bfloat16* WcatT  = (__hip_bfloat16*)carve(256 * 256 * 2);
  __hip_bfloat16* WmT    = (__hip_bfloat16*)carve(256 * 128 * 2);
  __hip_bfloat16* W1T    = (__hip_bfloat16*)carve(256 * 256 * 2);
  __hip_bfloat16* W2T    = (__hip_bfloat16*)carve(128 * 256 * 2);
  float*          bc     = (float*)carve(256 * 4);

  prep_all<<<CONV_BLOCKS + 256, 256, 0, stream>>>(
      table, tb, Wu, Wm, W1, W2, bu, bm, WcatT, WmT, W1T, W2T, bc);
  fused_mlp<<<3 * BATCH_N / 64, 512, 0, stream>>>(
      users, tb, pos_ids, neg_ids, nbr_ids, WcatT, WmT, W1T, W2T,
      bc, bm, b1, b2, out);
}

// Round 3
// 199.179 us; speedup vs baseline: 1.1528x; 1.1528x over previous
//
#include <hip/hip_runtime.h>
#include <hip/hip_bf16.h>

// Problem constants (from reference)
#define BATCH_N   16384
#define FEAT      128      // MOVIE_FEAT == USER_FEAT
#define NNBR      50
#define NUM_MOVIES_N 100000

typedef short  short8  __attribute__((ext_vector_type(8)));
typedef float  floatx4 __attribute__((ext_vector_type(4)));
typedef unsigned int u32;

__device__ __forceinline__ __hip_bfloat16 f2bf(float x) { return __float2bfloat16(x); }
__device__ __forceinline__ float bfb2f(short s) {
  union { u32 u; float f; } c; c.u = ((u32)(unsigned short)s) << 16; return c.f;
}

// async global->LDS 16B DMA. LDS dst must be wave-uniform base + lane*16
// (m104), so the XOR swizzle is applied to the SOURCE index.
__device__ __forceinline__ void gld16(const __hip_bfloat16* g, __hip_bfloat16* l) {
  __builtin_amdgcn_global_load_lds(
      (const __attribute__((address_space(1))) u32*)g,
      (__attribute__((address_space(3))) u32*)l, 16, 0, 0);
}

__device__ __forceinline__ floatx4 mfma16(short8 a, short8 b, floatx4 c) {
  return __builtin_amdgcn_mfma_f32_16x16x32_bf16(a, b, c, 0, 0, 0);
}

// ---------------------------------------------------------------------------
// prep_all: fused (a) fp32 movie_table -> bf16 copy and (b) bf16 transposed
// weights Wt[n][k] + fused bias bu+bm. One launch instead of two.
// blocks [0,6250): conv;  [6250,6506): weight prep.
// ---------------------------------------------------------------------------
#define CONV_BLOCKS (NUM_MOVIES_N * FEAT / (256 * 8))   // 6250
__global__ __launch_bounds__(256) void prep_all(
    const float* __restrict__ t, __hip_bfloat16* __restrict__ tb,
    const float* __restrict__ Wu, const float* __restrict__ Wm,
    const float* __restrict__ W1, const float* __restrict__ W2,
    const float* __restrict__ bu, const float* __restrict__ bm,
    __hip_bfloat16* __restrict__ WcatT, __hip_bfloat16* __restrict__ WmT,
    __hip_bfloat16* __restrict__ W1T,  __hip_bfloat16* __restrict__ W2T,
    float* __restrict__ bc) {
  int bid = blockIdx.x;
  if (bid < CONV_BLOCKS) {
    size_t i = ((size_t)bid * 256 + threadIdx.x) * 8;
    float4 v0 = *(const float4*)(t + i);
    float4 v1 = *(const float4*)(t + i + 4);
    __hip_bfloat16 o[8];
    o[0] = f2bf(v0.x); o[1] = f2bf(v0.y); o[2] = f2bf(v0.z); o[3] = f2bf(v0.w);
    o[4] = f2bf(v1.x); o[5] = f2bf(v1.y); o[6] = f2bf(v1.z); o[7] = f2bf(v1.w);
    *(short8*)(tb + i) = *(short8*)o;
  } else {
    int idx = (bid - CONV_BLOCKS) * 256 + threadIdx.x;   // 0..65535
    int n = idx & 255, k = idx >> 8;
    float v = (k < 128) ? Wu[k * 256 + n] : Wm[(k - 128) * 256 + n];
    WcatT[n * 256 + k] = f2bf(v);
    W1T[n * 256 + k]   = f2bf(W1[k * 256 + n]);
    if (k < 128) WmT[n * 128 + k] = f2bf(Wm[k * 256 + n]);
    if (idx < 32768) {
      int k2 = idx >> 7, n2 = idx & 127;
      W2T[n2 * 256 + k2] = f2bf(W2[k2 * 128 + n2]);
    }
    if (idx < 256) bc[idx] = bu[idx] + bm[idx];
  }
}

// ---------------------------------------------------------------------------
// layer: one GEMM layer on a 64-row LDS tile with B persistent in VGPRs.
//   Ain (LDS): 64 rows x K0, XOR-swizzled (16B slot s holds chunk s^(r&7)).
//   Wt: global [NCOL][K0] bf16 (L2-hot; ~16 KB/wave loaded ONCE per layer).
// 8 waves split N: wave w owns JN*16 cols (JN = NCOL/128).
// 4 iters x 16 rows: KK ds_read_b128 + 2*KK*JN MFMA; epilogue -> LDS
// (swizzled, 256-col) or global fp32 (128-col).
// ---------------------------------------------------------------------------
template <int K0, int NCOL, bool RELU, bool TOGLB>
__device__ __forceinline__ void layer(
    const __hip_bfloat16* Ain,
    const __hip_bfloat16* __restrict__ Wt, const float* __restrict__ bias,
    __hip_bfloat16* Olds, float* __restrict__ Oglb,
    int wid, int quad, int lrow) {
  constexpr int KK = K0 / 32;
  constexpr int JN = NCOL / 128;
  const int c0 = wid * JN * 16;

  short8 bfr[JN][KK];
  float  bv[JN];
  #pragma unroll
  for (int j = 0; j < JN; ++j) {
    #pragma unroll
    for (int kc = 0; kc < KK; ++kc)
      bfr[j][kc] = *(const short8*)(Wt + (size_t)(c0 + j * 16 + lrow) * K0 +
                                    kc * 32 + quad * 8);
    bv[j] = bias[c0 + j * 16 + lrow];
  }

  #pragma unroll
  for (int it = 0; it < 4; ++it) {
    int r = it * 16 + lrow;
    short8 af[KK];
    #pragma unroll
    for (int kc = 0; kc < KK; ++kc)
      af[kc] = *(const short8*)&Ain[r * K0 + (((kc * 4 + quad) ^ (r & 7)) << 3)];
    floatx4 pa[JN], pb[JN];
    #pragma unroll
    for (int j = 0; j < JN; ++j) { pa[j] = {}; pb[j] = {}; }
    #pragma unroll
    for (int kc = 0; kc < KK; kc += 2)
      #pragma unroll
      for (int j = 0; j < JN; ++j) {
        pa[j] = mfma16(af[kc],     bfr[j][kc],     pa[j]);
        pb[j] = mfma16(af[kc + 1], bfr[j][kc + 1], pb[j]);
      }
    #pragma unroll
    for (int j = 0; j < JN; ++j) {
      floatx4 a = pa[j] + pb[j];
      int col = c0 + j * 16 + lrow;
      #pragma unroll
      for (int rr = 0; rr < 4; ++rr) {
        int row = it * 16 + quad * 4 + rr;
        float v = a[rr] + bv[j];
        if (RELU) v = fmaxf(v, 0.f);
        if (TOGLB) {
          Oglb[(size_t)row * NCOL + col] = v;
        } else {
          int ch = col >> 3;
          Olds[row * 256 + (((ch ^ (row & 7)) << 3) | (col & 7))] = f2bf(v);
        }
      }
    }
  }
}

// ---------------------------------------------------------------------------
// fused_mlp: one block = 64 rows of stream s (0 user / 1 pos / 2 neg),
// all 3 layers; B per layer in VGPRs, A/E/H in LDS; 3 barriers per block.
//
// Pin history (do not change without re-reading):
//   R10: launch_bounds(512,2) alone -> scheduler targeted 4 w/EU, 88 VGPR,
//        B-loads sunk into loop, MfmaUtil 10.7%.
//   R12: amdgpu_waves_per_eu(4,4) -> allocator dropped to the 64-VGPR bucket,
//        persistent-B spilled to scratch (WRITE_SIZE 24.6 -> 129.6 MB).
//   (2,2) is the ONLY verified-good codegen: VGPR=100, no spill. HW residency
//   is set by the actual VGPR count (100 -> 5 waves/EU allowed), so two
//   8-wave blocks can still co-reside per CU; the pin only caps the compiler.
//
// R13 (this round): R11's in-block gather + R12's front-loaded stream map
// (s0 = blocks [0,256) so all gathers start at t=0, co-resident with s1/s2
// MFMA blocks), with the (2,2) pin restored.
// ---------------------------------------------------------------------------
__global__ __launch_bounds__(512)
__attribute__((amdgpu_waves_per_eu(2, 2)))
void fused_mlp(
    const float* __restrict__ users,
    const __hip_bfloat16* __restrict__ tb,
    const int* __restrict__ pos_ids, const int* __restrict__ neg_ids,
    const int* __restrict__ nbr_ids,
    const __hip_bfloat16* __restrict__ WcatT,
    const __hip_bfloat16* __restrict__ WmT,
    const __hip_bfloat16* __restrict__ W1T,
    const __hip_bfloat16* __restrict__ W2T,
    const float* __restrict__ bc, const float* __restrict__ bmv,
    const float* __restrict__ b1, const float* __restrict__ b2,
    float* __restrict__ out) {
  __shared__ __hip_bfloat16 A_lds[64 * 256];   // 32 KB: A, then H
  __shared__ __hip_bfloat16 E_lds[64 * 256];   // 32 KB: E

  const int t    = threadIdx.x;
  const int lane = t & 63, wid = t >> 6;       // wid 0..7
  const int quad = lane >> 4, lrow = lane & 15;

  // front-loaded stream mapping: [0,256) -> s0; [256,768) -> s1/s2 interleaved
  int s, tile;
  if (blockIdx.x < 256) { s = 0; tile = blockIdx.x; }
  else { int k = blockIdx.x - 256; s = 1 + (k & 1); tile = k >> 1; }
  const long m0 = (long)tile * 64;

  // ---- stage A tile ----
  if (s == 0) {
    // in-block neighbor gather + user convert (was gather_user kernel).
    for (int rr = 0; rr < 8; ++rr) {
      const int r = (wid << 3) | rr;
      const size_t grow = (size_t)(m0 + r);
      const int* nb = nbr_ids + grow * NNBR;
      float acc[8] = {0.f, 0.f, 0.f, 0.f, 0.f, 0.f, 0.f, 0.f};
      #pragma unroll
      for (int it = 0; it < 13; ++it) {
        int j = (it << 2) + quad;
        if (j < NNBR) {
          int id = nb[j];
          short8 v = *(const short8*)(tb + (size_t)id * FEAT + (lrow << 3));
          #pragma unroll
          for (int e = 0; e < 8; ++e) acc[e] += bfb2f(v[e]);
        }
      }
      __hip_bfloat16 o[8];
      #pragma unroll
      for (int e = 0; e < 8; ++e) {
        float v = acc[e];
        v += __shfl_xor(v, 16, 64);
        v += __shfl_xor(v, 32, 64);
        o[e] = f2bf(v * (1.f / NNBR));
      }
      if (quad == 0) {
        int ch = 16 + lrow;                    // cols [128,256), one 16B chunk
        *(short8*)(A_lds + r * 256 + ((ch ^ (r & 7)) << 3)) = *(short8*)o;
      }
      // users fp32 -> bf16, cols [0,128): lane covers 2 consecutive cols
      float2 uv = ((const float2*)(users + grow * FEAT))[lane];
      __hip_bfloat162 t0; t0.x = f2bf(uv.x); t0.y = f2bf(uv.y);
      int col = lane << 1, ch2 = col >> 3;
      *(__hip_bfloat162*)(A_lds + r * 256 + ((ch2 ^ (r & 7)) << 3) + (col & 7)) = t0;
    }
  } else {
    const int* ids = (s == 1) ? pos_ids : neg_ids;
    #pragma unroll
    for (int i = 0; i < 2; ++i) {
      int c = t + i * 512;                     // 1024 slots: r=c>>4, sl=c&15
      int r = c >> 4, sl = c & 15;
      int id = ids[m0 + r];
      gld16(tb + ((size_t)id << 7) + ((sl ^ (r & 7)) << 3),
            A_lds + (c << 3));
    }
  }
  __syncthreads();                             // A staged (vmcnt(0) drain / LDS writes)

  // ---- layer 0 -> E_lds (no relu) ----
  if (s == 0)
    layer<256, 256, false, false>(A_lds, WcatT, bc, E_lds, nullptr,
                                  wid, quad, lrow);
  else
    layer<128, 256, false, false>(A_lds, WmT, bmv, E_lds, nullptr,
                                  wid, quad, lrow);
  __syncthreads();                             // E complete (A reads done)

  // ---- layer 1: H = relu(E @ W1^T + b1) -> A_lds ----
  layer<256, 256, true, false>(E_lds, W1T, b1, A_lds, nullptr,
                               wid, quad, lrow);
  __syncthreads();                             // H complete

  // ---- layer 2: out = relu(H @ W2^T + b2) -> global fp32 ----
  layer<256, 128, true, true>(A_lds, W2T, b2, nullptr,
                              out + ((size_t)s * BATCH_N + m0) * 128,
                              wid, quad, lrow);
}

// ---------------------------------------------------------------------------
extern "C" void kernel_launch(void* const* d_in, const int* in_sizes, int n_in,
                              void* d_out, int out_size, void* d_ws, size_t ws_size,
                              hipStream_t stream) {
  const float* users   = (const float*)d_in[0];
  // d_in[1] pos_movies, d_in[2] neg_movies, d_in[3] user_ids: unused by ref
  const int*   pos_ids = (const int*)d_in[4];
  const int*   neg_ids = (const int*)d_in[5];
  const int*   nbr_ids = (const int*)d_in[6];
  const float* table   = (const float*)d_in[7];
  const float* Wu = (const float*)d_in[8];
  const float* bu = (const float*)d_in[9];
  const float* Wm = (const float*)d_in[10];
  const float* bm = (const float*)d_in[11];
  const float* W1 = (const float*)d_in[12];
  const float* b1 = (const float*)d_in[13];
  const float* W2 = (const float*)d_in[14];
  const float* b2 = (const float*)d_in[15];
  float* out = (float*)d_out;

  // workspace carve (all 256B aligned). Total ~26 MB.
  char* p = (char*)d_ws;
  auto carve = [&](size_t bytes) { char* r = p; p += (bytes + 255) & ~(size_t)255; return r; };
  __hip_bfloat16* tb     = (__hip_bfloat16*)carve((size_t)NUM_MOVIES_N * FEAT * 2);
  __hip_bfloat16* WcatT  = (__hip_bfloat16*)carve(256 * 256 * 2);
  __hip_bfloat16* WmT    = (__hip_bfloat16*)carve(256 * 128 * 2);
  __hip_bfloat16* W1T    = (__hip_bfloat16*)carve(256 * 256 * 2);
  __hip_bfloat16* W2T    = (__hip_bfloat16*)carve(128 * 256 * 2);
  float*          bc     = (float*)carve(256 * 4);

  prep_all<<<CONV_BLOCKS + 256, 256, 0, stream>>>(
      table, tb, Wu, Wm, W1, W2, bu, bm, WcatT, WmT, W1T, W2T, bc);
  fused_mlp<<<3 * BATCH_N / 64, 512, 0, stream>>>(
      users, tb, pos_ids, neg_ids, nbr_ids, WcatT, WmT, W1T, W2T,
      bc, bm, b1, b2, out);
}

// Round 4
// 195.229 us; speedup vs baseline: 1.1761x; 1.0202x over previous
//
#include <hip/hip_runtime.h>
#include <hip/hip_bf16.h>

// Problem constants (from reference)
#define BATCH_N   16384
#define FEAT      128      // MOVIE_FEAT == USER_FEAT
#define NNBR      50
#define NUM_MOVIES_N 100000

typedef short  short8  __attribute__((ext_vector_type(8)));
typedef float  floatx4 __attribute__((ext_vector_type(4)));
typedef unsigned int u32;

__device__ __forceinline__ __hip_bfloat16 f2bf(float x) { return __float2bfloat16(x); }
__device__ __forceinline__ float bfb2f(short s) {
  union { u32 u; float f; } c; c.u = ((u32)(unsigned short)s) << 16; return c.f;
}

// async global->LDS 16B DMA. LDS dst must be wave-uniform base + lane*16
// (m104), so the XOR swizzle is applied to the SOURCE index.
__device__ __forceinline__ void gld16(const __hip_bfloat16* g, __hip_bfloat16* l) {
  __builtin_amdgcn_global_load_lds(
      (const __attribute__((address_space(1))) u32*)g,
      (__attribute__((address_space(3))) u32*)l, 16, 0, 0);
}

__device__ __forceinline__ floatx4 mfma16(short8 a, short8 b, floatx4 c) {
  return __builtin_amdgcn_mfma_f32_16x16x32_bf16(a, b, c, 0, 0, 0);
}

// ---------------------------------------------------------------------------
// prep_all: fused (a) fp32 movie_table -> bf16 copy and (b) bf16 transposed
// weights Wt[n][k] + fused bias bu+bm. One launch instead of two.
// blocks [0,6250): conv;  [6250,6506): weight prep.
// ---------------------------------------------------------------------------
#define CONV_BLOCKS (NUM_MOVIES_N * FEAT / (256 * 8))   // 6250
__global__ __launch_bounds__(256) void prep_all(
    const float* __restrict__ t, __hip_bfloat16* __restrict__ tb,
    const float* __restrict__ Wu, const float* __restrict__ Wm,
    const float* __restrict__ W1, const float* __restrict__ W2,
    const float* __restrict__ bu, const float* __restrict__ bm,
    __hip_bfloat16* __restrict__ WcatT, __hip_bfloat16* __restrict__ WmT,
    __hip_bfloat16* __restrict__ W1T,  __hip_bfloat16* __restrict__ W2T,
    float* __restrict__ bc) {
  int bid = blockIdx.x;
  if (bid < CONV_BLOCKS) {
    size_t i = ((size_t)bid * 256 + threadIdx.x) * 8;
    float4 v0 = *(const float4*)(t + i);
    float4 v1 = *(const float4*)(t + i + 4);
    __hip_bfloat16 o[8];
    o[0] = f2bf(v0.x); o[1] = f2bf(v0.y); o[2] = f2bf(v0.z); o[3] = f2bf(v0.w);
    o[4] = f2bf(v1.x); o[5] = f2bf(v1.y); o[6] = f2bf(v1.z); o[7] = f2bf(v1.w);
    *(short8*)(tb + i) = *(short8*)o;
  } else {
    int idx = (bid - CONV_BLOCKS) * 256 + threadIdx.x;   // 0..65535
    int n = idx & 255, k = idx >> 8;
    float v = (k < 128) ? Wu[k * 256 + n] : Wm[(k - 128) * 256 + n];
    WcatT[n * 256 + k] = f2bf(v);
    W1T[n * 256 + k]   = f2bf(W1[k * 256 + n]);
    if (k < 128) WmT[n * 128 + k] = f2bf(Wm[k * 256 + n]);
    if (idx < 32768) {
      int k2 = idx >> 7, n2 = idx & 127;
      W2T[n2 * 256 + k2] = f2bf(W2[k2 * 128 + n2]);
    }
    if (idx < 256) bc[idx] = bu[idx] + bm[idx];
  }
}

// ---------------------------------------------------------------------------
// layer: one GEMM layer on a 64-row LDS tile with B persistent in VGPRs.
//   Ain (LDS): 64 rows x K0, XOR-swizzled (16B slot s holds chunk s^(r&7)).
//   Wt: global [NCOL][K0] bf16 (L2-hot; ~16 KB/wave loaded ONCE per layer).
// 8 waves split N: wave w owns JN*16 cols (JN = NCOL/128).
// 4 iters x 16 rows: KK ds_read_b128 + 2*KK*JN MFMA; epilogue -> LDS
// (swizzled, 256-col) or global fp32 (128-col).
// ---------------------------------------------------------------------------
template <int K0, int NCOL, bool RELU, bool TOGLB>
__device__ __forceinline__ void layer(
    const __hip_bfloat16* Ain,
    const __hip_bfloat16* __restrict__ Wt, const float* __restrict__ bias,
    __hip_bfloat16* Olds, float* __restrict__ Oglb,
    int wid, int quad, int lrow) {
  constexpr int KK = K0 / 32;
  constexpr int JN = NCOL / 128;
  const int c0 = wid * JN * 16;

  short8 bfr[JN][KK];
  float  bv[JN];
  #pragma unroll
  for (int j = 0; j < JN; ++j) {
    #pragma unroll
    for (int kc = 0; kc < KK; ++kc)
      bfr[j][kc] = *(const short8*)(Wt + (size_t)(c0 + j * 16 + lrow) * K0 +
                                    kc * 32 + quad * 8);
    bv[j] = bias[c0 + j * 16 + lrow];
  }

  #pragma unroll
  for (int it = 0; it < 4; ++it) {
    int r = it * 16 + lrow;
    short8 af[KK];
    #pragma unroll
    for (int kc = 0; kc < KK; ++kc)
      af[kc] = *(const short8*)&Ain[r * K0 + (((kc * 4 + quad) ^ (r & 7)) << 3)];
    floatx4 pa[JN], pb[JN];
    #pragma unroll
    for (int j = 0; j < JN; ++j) { pa[j] = {}; pb[j] = {}; }
    #pragma unroll
    for (int kc = 0; kc < KK; kc += 2)
      #pragma unroll
      for (int j = 0; j < JN; ++j) {
        pa[j] = mfma16(af[kc],     bfr[j][kc],     pa[j]);
        pb[j] = mfma16(af[kc + 1], bfr[j][kc + 1], pb[j]);
      }
    #pragma unroll
    for (int j = 0; j < JN; ++j) {
      floatx4 a = pa[j] + pb[j];
      int col = c0 + j * 16 + lrow;
      #pragma unroll
      for (int rr = 0; rr < 4; ++rr) {
        int row = it * 16 + quad * 4 + rr;
        float v = a[rr] + bv[j];
        if (RELU) v = fmaxf(v, 0.f);
        if (TOGLB) {
          Oglb[(size_t)row * NCOL + col] = v;
        } else {
          int ch = col >> 3;
          Olds[row * 256 + (((ch ^ (row & 7)) << 3) | (col & 7))] = f2bf(v);
        }
      }
    }
  }
}

// ---------------------------------------------------------------------------
// fused_mlp: one block = 64 rows of stream s (0 user / 1 pos / 2 neg),
// all 3 layers; B per layer in VGPRs, A/E/H in LDS; 3 barriers per block.
//
// Pin history (do not change without re-reading):
//   R10: launch_bounds(512,2) alone -> scheduler targeted 4 w/EU, 88 VGPR,
//        B-loads sunk into loop, MfmaUtil 10.7%.
//   R12: amdgpu_waves_per_eu(4,4) -> allocator dropped to the 64-VGPR bucket,
//        persistent-B spilled to scratch (WRITE_SIZE 24.6 -> 129.6 MB).
//   (2,2) is the ONLY verified-good codegen: no spill. HW residency follows
//   actual VGPR count; the pin only caps the compiler.
//
// R14 (this round): the gather is MLP-bound — R13 counters closed the model:
// 13 loads in flight/wave x 8 waves x 16 B = 1.66 KB/CU -> 1.13 TB/s
// (measured 1.58 incl. other traffic); BW-bound needs ~9.2 KB/CU. Fix: the
// s0 gather processes its 8 rows as 4 PAIRS, hoisting both rows' 26 loads
// (clamped j, masked accumulate) into one unrolled batch -> 2x in flight.
// VGPR peak in the gather section ~170 < 256 budget, dead before layers.
// ---------------------------------------------------------------------------
__global__ __launch_bounds__(512)
__attribute__((amdgpu_waves_per_eu(2, 2)))
void fused_mlp(
    const float* __restrict__ users,
    const __hip_bfloat16* __restrict__ tb,
    const int* __restrict__ pos_ids, const int* __restrict__ neg_ids,
    const int* __restrict__ nbr_ids,
    const __hip_bfloat16* __restrict__ WcatT,
    const __hip_bfloat16* __restrict__ WmT,
    const __hip_bfloat16* __restrict__ W1T,
    const __hip_bfloat16* __restrict__ W2T,
    const float* __restrict__ bc, const float* __restrict__ bmv,
    const float* __restrict__ b1, const float* __restrict__ b2,
    float* __restrict__ out) {
  __shared__ __hip_bfloat16 A_lds[64 * 256];   // 32 KB: A, then H
  __shared__ __hip_bfloat16 E_lds[64 * 256];   // 32 KB: E

  const int t    = threadIdx.x;
  const int lane = t & 63, wid = t >> 6;       // wid 0..7
  const int quad = lane >> 4, lrow = lane & 15;

  // front-loaded stream mapping: [0,256) -> s0; [256,768) -> s1/s2 interleaved
  int s, tile;
  if (blockIdx.x < 256) { s = 0; tile = blockIdx.x; }
  else { int k = blockIdx.x - 256; s = 1 + (k & 1); tile = k >> 1; }
  const long m0 = (long)tile * 64;

  // ---- stage A tile ----
  if (s == 0) {
    // in-block neighbor gather, row-PAIR interleaved for 26 loads in flight.
    #pragma unroll 1
    for (int rp = 0; rp < 4; ++rp) {
      const int r0 = (wid << 3) | (rp << 1);
      const int r1 = r0 + 1;
      const size_t g0 = (size_t)(m0 + r0);
      const size_t g1 = g0 + 1;
      const int* nb0 = nbr_ids + g0 * NNBR;
      const int* nb1 = nbr_ids + g1 * NNBR;
      // user rows (independent loads, issue early)
      float2 uv0 = ((const float2*)(users + g0 * FEAT))[lane];
      float2 uv1 = ((const float2*)(users + g1 * FEAT))[lane];
      // batch-issue all 26 gather loads (statically indexed -> registers)
      short8 v0[13], v1[13];
      #pragma unroll
      for (int it = 0; it < 13; ++it) {
        int j = (it << 2) + quad;
        int jj = (j < NNBR) ? j : (NNBR - 1);  // clamp; masked in accumulate
        v0[it] = *(const short8*)(tb + (size_t)nb0[jj] * FEAT + (lrow << 3));
        v1[it] = *(const short8*)(tb + (size_t)nb1[jj] * FEAT + (lrow << 3));
      }
      float acc0[8] = {0.f, 0.f, 0.f, 0.f, 0.f, 0.f, 0.f, 0.f};
      float acc1[8] = {0.f, 0.f, 0.f, 0.f, 0.f, 0.f, 0.f, 0.f};
      #pragma unroll
      for (int it = 0; it < 13; ++it) {
        int j = (it << 2) + quad;
        if (j < NNBR) {
          #pragma unroll
          for (int e = 0; e < 8; ++e) {
            acc0[e] += bfb2f(v0[it][e]);
            acc1[e] += bfb2f(v1[it][e]);
          }
        }
      }
      __hip_bfloat16 o0[8], o1[8];
      #pragma unroll
      for (int e = 0; e < 8; ++e) {
        float a0 = acc0[e], a1 = acc1[e];
        a0 += __shfl_xor(a0, 16, 64);
        a0 += __shfl_xor(a0, 32, 64);
        a1 += __shfl_xor(a1, 16, 64);
        a1 += __shfl_xor(a1, 32, 64);
        o0[e] = f2bf(a0 * (1.f / NNBR));
        o1[e] = f2bf(a1 * (1.f / NNBR));
      }
      if (quad == 0) {
        int ch = 16 + lrow;                    // cols [128,256), one 16B chunk
        *(short8*)(A_lds + r0 * 256 + ((ch ^ (r0 & 7)) << 3)) = *(short8*)o0;
        *(short8*)(A_lds + r1 * 256 + ((ch ^ (r1 & 7)) << 3)) = *(short8*)o1;
      }
      // users fp32 -> bf16, cols [0,128): lane covers 2 consecutive cols
      __hip_bfloat162 t0; t0.x = f2bf(uv0.x); t0.y = f2bf(uv0.y);
      __hip_bfloat162 t1; t1.x = f2bf(uv1.x); t1.y = f2bf(uv1.y);
      int col = lane << 1, ch2 = col >> 3;
      *(__hip_bfloat162*)(A_lds + r0 * 256 + ((ch2 ^ (r0 & 7)) << 3) + (col & 7)) = t0;
      *(__hip_bfloat162*)(A_lds + r1 * 256 + ((ch2 ^ (r1 & 7)) << 3) + (col & 7)) = t1;
    }
  } else {
    const int* ids = (s == 1) ? pos_ids : neg_ids;
    #pragma unroll
    for (int i = 0; i < 2; ++i) {
      int c = t + i * 512;                     // 1024 slots: r=c>>4, sl=c&15
      int r = c >> 4, sl = c & 15;
      int id = ids[m0 + r];
      gld16(tb + ((size_t)id << 7) + ((sl ^ (r & 7)) << 3),
            A_lds + (c << 3));
    }
  }
  __syncthreads();                             // A staged (vmcnt(0) drain / LDS writes)

  // ---- layer 0 -> E_lds (no relu) ----
  if (s == 0)
    layer<256, 256, false, false>(A_lds, WcatT, bc, E_lds, nullptr,
                                  wid, quad, lrow);
  else
    layer<128, 256, false, false>(A_lds, WmT, bmv, E_lds, nullptr,
                                  wid, quad, lrow);
  __syncthreads();                             // E complete (A reads done)

  // ---- layer 1: H = relu(E @ W1^T + b1) -> A_lds ----
  layer<256, 256, true, false>(E_lds, W1T, b1, A_lds, nullptr,
                               wid, quad, lrow);
  __syncthreads();                             // H complete

  // ---- layer 2: out = relu(H @ W2^T + b2) -> global fp32 ----
  layer<256, 128, true, true>(A_lds, W2T, b2, nullptr,
                              out + ((size_t)s * BATCH_N + m0) * 128,
                              wid, quad, lrow);
}

// ---------------------------------------------------------------------------
extern "C" void kernel_launch(void* const* d_in, const int* in_sizes, int n_in,
                              void* d_out, int out_size, void* d_ws, size_t ws_size,
                              hipStream_t stream) {
  const float* users   = (const float*)d_in[0];
  // d_in[1] pos_movies, d_in[2] neg_movies, d_in[3] user_ids: unused by ref
  const int*   pos_ids = (const int*)d_in[4];
  const int*   neg_ids = (const int*)d_in[5];
  const int*   nbr_ids = (const int*)d_in[6];
  const float* table   = (const float*)d_in[7];
  const float* Wu = (const float*)d_in[8];
  const float* bu = (const float*)d_in[9];
  const float* Wm = (const float*)d_in[10];
  const float* bm = (const float*)d_in[11];
  const float* W1 = (const float*)d_in[12];
  const float* b1 = (const float*)d_in[13];
  const float* W2 = (const float*)d_in[14];
  const float* b2 = (const float*)d_in[15];
  float* out = (float*)d_out;

  // workspace carve (all 256B aligned). Total ~26 MB.
  char* p = (char*)d_ws;
  auto carve = [&](size_t bytes) { char* r = p; p += (bytes + 255) & ~(size_t)255; return r; };
  __hip_bfloat16* tb     = (__hip_bfloat16*)carve((size_t)NUM_MOVIES_N * FEAT * 2);
  __hip_bfloat16* WcatT  = (__hip_bfloat16*)carve(256 * 256 * 2);
  __hip_bfloat16* WmT    = (__hip_bfloat16*)carve(256 * 128 * 2);
  __hip_bfloat16* W1T    = (__hip_bfloat16*)carve(256 * 256 * 2);
  __hip_bfloat16* W2T    = (__hip_bfloat16*)carve(128 * 256 * 2);
  float*          bc     = (float*)carve(256 * 4);

  prep_all<<<CONV_BLOCKS + 256, 256, 0, stream>>>(
      table, tb, Wu, Wm, W1, W2, bu, bm, WcatT, WmT, W1T, W2T, bc);
  fused_mlp<<<3 * BATCH_N / 64, 512, 0, stream>>>(
      users, tb, pos_ids, neg_ids, nbr_ids, WcatT, WmT, W1T, W2T,
      bc, bm, b1, b2, out);
}

// Round 5
// 193.443 us; speedup vs baseline: 1.1869x; 1.0092x over previous
//
#include <hip/hip_runtime.h>
#include <hip/hip_bf16.h>

// Problem constants (from reference)
#define BATCH_N   16384
#define FEAT      128      // MOVIE_FEAT == USER_FEAT
#define NNBR      50
#define NUM_MOVIES_N 100000

typedef short  short8  __attribute__((ext_vector_type(8)));
typedef float  floatx4 __attribute__((ext_vector_type(4)));
typedef unsigned int u32;

__device__ __forceinline__ __hip_bfloat16 f2bf(float x) { return __float2bfloat16(x); }
__device__ __forceinline__ float bfb2f(short s) {
  union { u32 u; float f; } c; c.u = ((u32)(unsigned short)s) << 16; return c.f;
}

// async global->LDS 16B DMA. HW writes wave-uniform base + lane*16 (m104);
// the per-lane pointer we pass must equal that form.
__device__ __forceinline__ void gld16(const __hip_bfloat16* g, __hip_bfloat16* l) {
  __builtin_amdgcn_global_load_lds(
      (const __attribute__((address_space(1))) u32*)g,
      (__attribute__((address_space(3))) u32*)l, 16, 0, 0);
}

__device__ __forceinline__ floatx4 mfma16(short8 a, short8 b, floatx4 c) {
  return __builtin_amdgcn_mfma_f32_16x16x32_bf16(a, b, c, 0, 0, 0);
}

#define WAITVM2 asm volatile("s_waitcnt vmcnt(2)" ::: "memory")
#define WAITVM0 asm volatile("s_waitcnt vmcnt(0)" ::: "memory")

// ---------------------------------------------------------------------------
// prep_all: fused (a) fp32 movie_table -> bf16 copy and (b) bf16 transposed
// weights Wt[n][k] + fused bias bu+bm. One launch instead of two.
// blocks [0,6250): conv;  [6250,6506): weight prep.
// ---------------------------------------------------------------------------
#define CONV_BLOCKS (NUM_MOVIES_N * FEAT / (256 * 8))   // 6250
__global__ __launch_bounds__(256) void prep_all(
    const float* __restrict__ t, __hip_bfloat16* __restrict__ tb,
    const float* __restrict__ Wu, const float* __restrict__ Wm,
    const float* __restrict__ W1, const float* __restrict__ W2,
    const float* __restrict__ bu, const float* __restrict__ bm,
    __hip_bfloat16* __restrict__ WcatT, __hip_bfloat16* __restrict__ WmT,
    __hip_bfloat16* __restrict__ W1T,  __hip_bfloat16* __restrict__ W2T,
    float* __restrict__ bc) {
  int bid = blockIdx.x;
  if (bid < CONV_BLOCKS) {
    size_t i = ((size_t)bid * 256 + threadIdx.x) * 8;
    float4 v0 = *(const float4*)(t + i);
    float4 v1 = *(const float4*)(t + i + 4);
    __hip_bfloat16 o[8];
    o[0] = f2bf(v0.x); o[1] = f2bf(v0.y); o[2] = f2bf(v0.z); o[3] = f2bf(v0.w);
    o[4] = f2bf(v1.x); o[5] = f2bf(v1.y); o[6] = f2bf(v1.z); o[7] = f2bf(v1.w);
    *(short8*)(tb + i) = *(short8*)o;
  } else {
    int idx = (bid - CONV_BLOCKS) * 256 + threadIdx.x;   // 0..65535
    int n = idx & 255, k = idx >> 8;
    float v = (k < 128) ? Wu[k * 256 + n] : Wm[(k - 128) * 256 + n];
    WcatT[n * 256 + k] = f2bf(v);
    W1T[n * 256 + k]   = f2bf(W1[k * 256 + n]);
    if (k < 128) WmT[n * 128 + k] = f2bf(Wm[k * 256 + n]);
    if (idx < 32768) {
      int k2 = idx >> 7, n2 = idx & 127;
      W2T[n2 * 256 + k2] = f2bf(W2[k2 * 128 + n2]);
    }
    if (idx < 256) bc[idx] = bu[idx] + bm[idx];
  }
}

// ---------------------------------------------------------------------------
// layer: one GEMM layer on a 64-row LDS tile with B persistent in VGPRs.
//   Ain (LDS): 64 rows x K0, XOR-swizzled (16B slot s holds chunk s^(r&7)).
//   Wt: global [NCOL][K0] bf16 (L2-hot; ~16 KB/wave loaded ONCE per layer).
// 8 waves split N: wave w owns JN*16 cols (JN = NCOL/128).
// 4 iters x 16 rows: KK ds_read_b128 + 2*KK*JN MFMA; epilogue -> LDS
// (swizzled, 256-col) or global fp32 (128-col).
// ---------------------------------------------------------------------------
template <int K0, int NCOL, bool RELU, bool TOGLB>
__device__ __forceinline__ void layer(
    const __hip_bfloat16* Ain,
    const __hip_bfloat16* __restrict__ Wt, const float* __restrict__ bias,
    __hip_bfloat16* Olds, float* __restrict__ Oglb,
    int wid, int quad, int lrow) {
  constexpr int KK = K0 / 32;
  constexpr int JN = NCOL / 128;
  const int c0 = wid * JN * 16;

  short8 bfr[JN][KK];
  float  bv[JN];
  #pragma unroll
  for (int j = 0; j < JN; ++j) {
    #pragma unroll
    for (int kc = 0; kc < KK; ++kc)
      bfr[j][kc] = *(const short8*)(Wt + (size_t)(c0 + j * 16 + lrow) * K0 +
                                    kc * 32 + quad * 8);
    bv[j] = bias[c0 + j * 16 + lrow];
  }

  #pragma unroll
  for (int it = 0; it < 4; ++it) {
    int r = it * 16 + lrow;
    short8 af[KK];
    #pragma unroll
    for (int kc = 0; kc < KK; ++kc)
      af[kc] = *(const short8*)&Ain[r * K0 + (((kc * 4 + quad) ^ (r & 7)) << 3)];
    floatx4 pa[JN], pb[JN];
    #pragma unroll
    for (int j = 0; j < JN; ++j) { pa[j] = {}; pb[j] = {}; }
    #pragma unroll
    for (int kc = 0; kc < KK; kc += 2)
      #pragma unroll
      for (int j = 0; j < JN; ++j) {
        pa[j] = mfma16(af[kc],     bfr[j][kc],     pa[j]);
        pb[j] = mfma16(af[kc + 1], bfr[j][kc + 1], pb[j]);
      }
    #pragma unroll
    for (int j = 0; j < JN; ++j) {
      floatx4 a = pa[j] + pb[j];
      int col = c0 + j * 16 + lrow;
      #pragma unroll
      for (int rr = 0; rr < 4; ++rr) {
        int row = it * 16 + quad * 4 + rr;
        float v = a[rr] + bv[j];
        if (RELU) v = fmaxf(v, 0.f);
        if (TOGLB) {
          Oglb[(size_t)row * NCOL + col] = v;
        } else {
          int ch = col >> 3;
          Olds[row * 256 + (((ch ^ (row & 7)) << 3) | (col & 7))] = f2bf(v);
        }
      }
    }
  }
}

// ---------------------------------------------------------------------------
// fused_mlp: one block = 64 rows of stream s (0 user / 1 pos / 2 neg),
// all 3 layers; B per layer in VGPRs, A/E/H in LDS; 3 barriers per block.
//
// Pin history (do not change without re-reading):
//   R10: launch_bounds(512,2) alone -> 88 VGPR, B-loads sunk. R12: (4,4) ->
//   64-VGPR bucket, persistent-B spilled (WRITE 24.6->129.6 MB). (2,2) is
//   the only verified-good codegen.
//
// R15 (this round): VGPR-staged gather can't scale MLP (R14: compiler held
// VGPR_Count at 100 and re-serialized the 26-load batch -> only 1.19x).
// Replace with async global_load_lds DMA, double-buffered in E_lds (free
// until layer 0). Per wave: 2x2KB buffers; chunk = 8 nbr rows = 2 gld16
// (1 KB each). All 400 ids bulk-loaded into 7 VGPRs, extracted by shfl ->
// no vmem inside the pipeline, so vmcnt counts are exact:
//   prologue: issue chunk0, chunk1           (outstanding = 4 gld16)
//   step k:   vmcnt(2)  -> chunk k retired   (k+1 in flight)
//             ds_read_b128 x2 + accumulate; row-end reduce/store
//             sched_barrier(0)               (no WAR on buffer reuse)
//             issue chunk k+2 into buf k&1
// In-flight lives in the DMA queue, not VGPRs -> the allocator can't
// serialize it. Accumulation order per lane identical to R14 (j = quad
// mod 4, increasing, separate adds) -> bit-identical numerics.
// ---------------------------------------------------------------------------
__global__ __launch_bounds__(512)
__attribute__((amdgpu_waves_per_eu(2, 2)))
void fused_mlp(
    const float* __restrict__ users,
    const __hip_bfloat16* __restrict__ tb,
    const int* __restrict__ pos_ids, const int* __restrict__ neg_ids,
    const int* __restrict__ nbr_ids,
    const __hip_bfloat16* __restrict__ WcatT,
    const __hip_bfloat16* __restrict__ WmT,
    const __hip_bfloat16* __restrict__ W1T,
    const __hip_bfloat16* __restrict__ W2T,
    const float* __restrict__ bc, const float* __restrict__ bmv,
    const float* __restrict__ b1, const float* __restrict__ b2,
    float* __restrict__ out) {
  __shared__ __hip_bfloat16 A_lds[64 * 256];   // 32 KB: A, then H
  __shared__ __hip_bfloat16 E_lds[64 * 256];   // 32 KB: gather staging, then E

  const int t    = threadIdx.x;
  const int lane = t & 63, wid = t >> 6;       // wid 0..7
  const int quad = lane >> 4, lrow = lane & 15;

  // front-loaded stream mapping: [0,256) -> s0; [256,768) -> s1/s2 interleaved
  int s, tile;
  if (blockIdx.x < 256) { s = 0; tile = blockIdx.x; }
  else { int k = blockIdx.x - 256; s = 1 + (k & 1); tile = k >> 1; }
  const long m0 = (long)tile * 64;

  // ---- stage A tile ----
  if (s == 0) {
    const int rbase = wid << 3;                      // wave owns rows rbase..+7
    const int* nbw = nbr_ids + (size_t)(m0 + rbase) * NNBR;   // 400 ids
    // bulk id load: 7 coalesced loads, lane l holds flat ids l, l+64, ...
    int idreg[7];
    #pragma unroll
    for (int w = 0; w < 7; ++w) {
      int fl = w * 64 + lane;
      idreg[w] = nbw[fl < 8 * NNBR ? fl : 8 * NNBR - 1];
    }
    // user rows (8 loads; retire under the pipeline, used at row ends)
    float2 uvr[8];
    #pragma unroll
    for (int r = 0; r < 8; ++r)
      uvr[r] = ((const float2*)(users + (size_t)(m0 + rbase + r) * FEAT))[lane];

    __hip_bfloat16* stg = E_lds + (wid << 11);       // 4 KB slice (2 x 2 KB)

    // id for 4 consecutive flat slots [fb, fb+3], lane picks fb+quad.
    auto getid = [&](int fb) -> int {
      int idx = fb + quad;
      int v = __shfl(idreg[fb >> 6], idx & 63, 64);
      if ((fb >> 6) != ((fb + 3) >> 6)) {
        int v2 = __shfl(idreg[(fb + 3) >> 6], idx & 63, 64);
        v = ((idx >> 6) == (fb >> 6)) ? v : v2;
      }
      return v;
    };
    // chunk k: rows j = c*8 + i*4 + quad (i=0,1), slice lrow; 2 x 1 KB DMA.
    auto issue = [&](int k) {
      int row = k / 7, c = k % 7;
      int id0 = getid(row * NNBR + c * 8);
      int id1 = getid(row * NNBR + c * 8 + 4);
      __hip_bfloat16* dst = stg + ((k & 1) << 10);   // buf k&1 (2 KB)
      gld16(tb + (size_t)id0 * FEAT + (lrow << 3), dst + (lane << 3));
      gld16(tb + (size_t)id1 * FEAT + (lrow << 3), dst + 512 + (lane << 3));
    };

    issue(0); issue(1);                              // fill pipeline (4 DMA)
    float acc[8] = {0.f, 0.f, 0.f, 0.f, 0.f, 0.f, 0.f, 0.f};
    #pragma unroll
    for (int k = 0; k < 56; ++k) {                   // row = k/7, c = k%7
      if (k < 55) { WAITVM2; } else { WAITVM0; }     // chunk k retired
      const __hip_bfloat16* b = stg + ((k & 1) << 10);
      int c = k % 7;
      short8 x0 = *(const short8*)(b + (lane << 3));           // j = c*8+quad
      if (c < 6) {
        short8 x1 = *(const short8*)(b + 512 + (lane << 3));   // j = c*8+4+quad
        #pragma unroll
        for (int e = 0; e < 8; ++e) { acc[e] += bfb2f(x0[e]); acc[e] += bfb2f(x1[e]); }
      } else if (quad < 2) {                         // j = 48+quad only
        #pragma unroll
        for (int e = 0; e < 8; ++e) acc[e] += bfb2f(x0[e]);
      }
      if (c == 6) {                                  // row complete
        int row = k / 7, r = rbase + row;
        __hip_bfloat16 o[8];
        #pragma unroll
        for (int e = 0; e < 8; ++e) {
          float v = acc[e];
          v += __shfl_xor(v, 16, 64);
          v += __shfl_xor(v, 32, 64);
          o[e] = f2bf(v * (1.f / NNBR));
          acc[e] = 0.f;
        }
        if (quad == 0) {
          int ch = 16 + lrow;                        // cols [128,256)
          *(short8*)(A_lds + r * 256 + ((ch ^ (r & 7)) << 3)) = *(short8*)o;
        }
        float2 uv = uvr[row];                        // cols [0,128)
        __hip_bfloat162 t0; t0.x = f2bf(uv.x); t0.y = f2bf(uv.y);
        int col = lane << 1, ch2 = col >> 3;
        *(__hip_bfloat162*)(A_lds + r * 256 + ((ch2 ^ (r & 7)) << 3) + (col & 7)) = t0;
      }
      __builtin_amdgcn_sched_barrier(0);             // ds_reads done before WAR reuse
      if (k + 2 < 56) issue(k + 2);
    }
  } else {
    const int* ids = (s == 1) ? pos_ids : neg_ids;
    #pragma unroll
    for (int i = 0; i < 2; ++i) {
      int c = t + i * 512;                     // 1024 slots: r=c>>4, sl=c&15
      int r = c >> 4, sl = c & 15;
      int id = ids[m0 + r];
      gld16(tb + ((size_t)id << 7) + ((sl ^ (r & 7)) << 3),
            A_lds + (c << 3));
    }
  }
  __syncthreads();                             // A staged (vmcnt(0) drain / LDS writes)

  // ---- layer 0 -> E_lds (no relu) ----
  if (s == 0)
    layer<256, 256, false, false>(A_lds, WcatT, bc, E_lds, nullptr,
                                  wid, quad, lrow);
  else
    layer<128, 256, false, false>(A_lds, WmT, bmv, E_lds, nullptr,
                                  wid, quad, lrow);
  __syncthreads();                             // E complete (A reads done)

  // ---- layer 1: H = relu(E @ W1^T + b1) -> A_lds ----
  layer<256, 256, true, false>(E_lds, W1T, b1, A_lds, nullptr,
                               wid, quad, lrow);
  __syncthreads();                             // H complete

  // ---- layer 2: out = relu(H @ W2^T + b2) -> global fp32 ----
  layer<256, 128, true, true>(A_lds, W2T, b2, nullptr,
                              out + ((size_t)s * BATCH_N + m0) * 128,
                              wid, quad, lrow);
}

// ---------------------------------------------------------------------------
extern "C" void kernel_launch(void* const* d_in, const int* in_sizes, int n_in,
                              void* d_out, int out_size, void* d_ws, size_t ws_size,
                              hipStream_t stream) {
  const float* users   = (const float*)d_in[0];
  // d_in[1] pos_movies, d_in[2] neg_movies, d_in[3] user_ids: unused by ref
  const int*   pos_ids = (const int*)d_in[4];
  const int*   neg_ids = (const int*)d_in[5];
  const int*   nbr_ids = (const int*)d_in[6];
  const float* table   = (const float*)d_in[7];
  const float* Wu = (const float*)d_in[8];
  const float* bu = (const float*)d_in[9];
  const float* Wm = (const float*)d_in[10];
  const float* bm = (const float*)d_in[11];
  const float* W1 = (const float*)d_in[12];
  const float* b1 = (const float*)d_in[13];
  const float* W2 = (const float*)d_in[14];
  const float* b2 = (const float*)d_in[15];
  float* out = (float*)d_out;

  // workspace carve (all 256B aligned). Total ~26 MB.
  char* p = (char*)d_ws;
  auto carve = [&](size_t bytes) { char* r = p; p += (bytes + 255) & ~(size_t)255; return r; };
  __hip_bfloat16* tb     = (__hip_bfloat16*)carve((size_t)NUM_MOVIES_N * FEAT * 2);
  __hip_bfloat16* WcatT  = (__hip_bfloat16*)carve(256 * 256 * 2);
  __hip_bfloat16* WmT    = (__hip_bfloat16*)carve(256 * 128 * 2);
  __hip_bfloat16* W1T    = (__hip_bfloat16*)carve(256 * 256 * 2);
  __hip_bfloat16* W2T    = (__hip_bfloat16*)carve(128 * 256 * 2);
  float*          bc     = (float*)carve(256 * 4);

  prep_all<<<CONV_BLOCKS + 256, 256, 0, stream>>>(
      table, tb, Wu, Wm, W1, W2, bu, bm, WcatT, WmT, W1T, W2T, bc);
  fused_mlp<<<3 * BATCH_N / 64, 512, 0, stream>>>(
      users, tb, pos_ids, neg_ids, nbr_ids, WcatT, WmT, W1T, W2T,
      bc, bm, b1, b2, out);
}